// Round 1
// baseline (653.636 us; speedup 1.0000x reference)
//
#include <hip/hip_runtime.h>

// segment_sum(h_t, batch, num_segments=10000)
//   h_t:   [N_NODES=1e6, FEAT=128] float32   (d_in[0])
//   batch: [N_NODES] int32, SORTED ascending (d_in[1])
//   out:   [10000, 128] float32              (d_out)
//
// R4: explicit 2-stage register double-buffer. R3 issued 12 loads then fully
// drained them through the STEP chain before the loop back-edge could reissue
// (WAR on v0..v7) -> avg ~6-8 outstanding loads/wave, one full HBM-latency
// bubble per 16 rows -> ~3.6 TB/s. R4 issues stage-B's 12 loads BEFORE
// consuming stage-A (alternating A/B, unrolled x2, all static register names),
// holding ~24 loads (384 B/lane) in flight steady-state. Also dropped the
// nontemporal hints (m13's 6.29 TB/s ubench used plain loads; nt unproven).
//
// dur_us decomposition (R4 analysis): ~495 us of the 638 is harness-fixed
// (2.048 GB poison fill @315 us visible in counters + input restore); the
// controllable segsum part is ~143 us (~3.6 TB/s). Target ~95-110 us.

#define FEAT 128
#define ROWS_PER_WAVE 128  // 7813 waves -> ~7.6 blocks/CU

typedef float vfloat4 __attribute__((ext_vector_type(4)));

__global__ __launch_bounds__(256) void segsum_kernel(
    const float* __restrict__ h,
    const int* __restrict__ batch,
    float* __restrict__ out,
    int n_rows) {
  const int wave = (blockIdx.x * blockDim.x + threadIdx.x) >> 6;
  const int lane = threadIdx.x & 63;
  const int sub = lane >> 5;         // which row of the pair this lane covers
  const int col = (lane & 31) * 4;   // 4 consecutive floats (16B coalesced)

  long long row0 = (long long)wave * ROWS_PER_WAVE;
  if (row0 >= n_rows) return;
  long long row_end = row0 + ROWS_PER_WAVE;
  if (row_end > n_rows) row_end = n_rows;

  vfloat4 acc = {0.0f, 0.0f, 0.0f, 0.0f};
  long long first = row0 + sub;
  int cur = batch[first < n_rows ? first : (n_rows - 1)];

#define STEP(B, V)                                        \
  {                                                       \
    const int b_ = (B);                                   \
    if (b_ != cur) { /* per-lane, rarely taken */         \
      float* dst = out + (long long)cur * FEAT + col;     \
      atomicAdd(dst + 0, acc.x);                          \
      atomicAdd(dst + 1, acc.y);                          \
      atomicAdd(dst + 2, acc.z);                          \
      atomicAdd(dst + 3, acc.w);                          \
      acc.x = 0.0f; acc.y = 0.0f;                         \
      acc.z = 0.0f; acc.w = 0.0f;                         \
      cur = b_;                                           \
    }                                                     \
    acc.x += (V).x; acc.y += (V).y;                       \
    acc.z += (V).z; acc.w += (V).w;                       \
  }

  // Two register stages (static names only -- no runtime-indexed arrays,
  // which would spill to scratch).
  int4 baA, bbA, bcA, bdA, baB, bbB, bcB, bdB;
  vfloat4 v0A, v1A, v2A, v3A, v4A, v5A, v6A, v7A;
  vfloat4 v0B, v1B, v2B, v3B, v4B, v5B, v6B, v7B;

  // Running pointers: no per-iteration 64-bit multiplies.
  const int* bcur = batch + row0;
  const float* hcur = h + (row0 + sub) * (long long)FEAT + col;
  long long r = row0;  // rows [row0, r) have been *loaded*

#define LOAD_STAGE(S)                                     \
  {                                                       \
    ba##S = *(const int4*)(bcur + 0);                     \
    bb##S = *(const int4*)(bcur + 4);                     \
    bc##S = *(const int4*)(bcur + 8);                     \
    bd##S = *(const int4*)(bcur + 12);                    \
    v0##S = *(const vfloat4*)(hcur + 0 * 2 * FEAT);       \
    v1##S = *(const vfloat4*)(hcur + 1 * 2 * FEAT);       \
    v2##S = *(const vfloat4*)(hcur + 2 * 2 * FEAT);       \
    v3##S = *(const vfloat4*)(hcur + 3 * 2 * FEAT);       \
    v4##S = *(const vfloat4*)(hcur + 4 * 2 * FEAT);       \
    v5##S = *(const vfloat4*)(hcur + 5 * 2 * FEAT);       \
    v6##S = *(const vfloat4*)(hcur + 6 * 2 * FEAT);       \
    v7##S = *(const vfloat4*)(hcur + 7 * 2 * FEAT);       \
    bcur += 16;                                           \
    hcur += 16 * FEAT;                                    \
    r += 16;                                              \
  }

#define CONSUME_STAGE(S)                                  \
  {                                                       \
    STEP(sub ? ba##S.y : ba##S.x, v0##S)                  \
    STEP(sub ? ba##S.w : ba##S.z, v1##S)                  \
    STEP(sub ? bb##S.y : bb##S.x, v2##S)                  \
    STEP(sub ? bb##S.w : bb##S.z, v3##S)                  \
    STEP(sub ? bc##S.y : bc##S.x, v4##S)                  \
    STEP(sub ? bc##S.w : bc##S.z, v5##S)                  \
    STEP(sub ? bd##S.y : bd##S.x, v6##S)                  \
    STEP(sub ? bd##S.w : bd##S.z, v7##S)                  \
  }

  // Software-pipelined main loop: next stage's 12 loads are issued BEFORE the
  // current stage is consumed, so ~24 dwordx4 stay in flight per lane and the
  // per-iteration latency drain of R3 disappears.
  if (r + 16 <= row_end) {
    LOAD_STAGE(A)
    for (;;) {
      if (r + 16 <= row_end) {
        LOAD_STAGE(B)
        CONSUME_STAGE(A)
      } else {
        CONSUME_STAGE(A)
        break;
      }
      if (r + 16 <= row_end) {
        LOAD_STAGE(A)
        CONSUME_STAGE(B)
      } else {
        CONSUME_STAGE(B)
        break;
      }
    }
  }

  // Pair tail (generic safety; with N_NODES=1e6 chunks are 128 or 64 rows)
  for (; r + 2 <= row_end; r += 2) {
    const int b = batch[r + sub];
    const vfloat4 v = *(const vfloat4*)(h + (r + sub) * (long long)FEAT + col);
    STEP(b, v)
  }
  // Odd last row
  if (r < row_end && sub == 0) {
    const int b = batch[r];
    const vfloat4 v = *(const vfloat4*)(h + r * (long long)FEAT + col);
    STEP(b, v)
  }
#undef STEP
#undef LOAD_STAGE
#undef CONSUME_STAGE

  // Final flush (run may continue into the next wave's chunk)
  {
    float* dst = out + (long long)cur * FEAT + col;
    atomicAdd(dst + 0, acc.x);
    atomicAdd(dst + 1, acc.y);
    atomicAdd(dst + 2, acc.z);
    atomicAdd(dst + 3, acc.w);
  }
}

extern "C" void kernel_launch(void* const* d_in, const int* in_sizes, int n_in,
                              void* d_out, int out_size, void* d_ws, size_t ws_size,
                              hipStream_t stream) {
  const float* h_t = (const float*)d_in[0];
  const int* batch = (const int*)d_in[1];
  float* out = (float*)d_out;
  const int n_rows = in_sizes[1];  // N_NODES

  // d_out is poisoned with 0xAA before every launch — zero it first.
  hipMemsetAsync(d_out, 0, (size_t)out_size * sizeof(float), stream);

  const int n_waves = (n_rows + ROWS_PER_WAVE - 1) / ROWS_PER_WAVE;
  const int block = 256;  // 4 waves/block
  const int waves_per_block = block / 64;
  const int grid = (n_waves + waves_per_block - 1) / waves_per_block;

  segsum_kernel<<<grid, block, 0, stream>>>(h_t, batch, out, n_rows);
}

// Round 2
// 643.494 us; speedup vs baseline: 1.0158x; 1.0158x over previous
//
#include <hip/hip_runtime.h>

// segment_sum(h_t, batch, num_segments=10000)
//   h_t:   [N_NODES=1e6, FEAT=128] float32   (d_in[0])
//   batch: [N_NODES] int32, SORTED ascending (d_in[1])
//   out:   [10000, 128] float32              (d_out)
//
// R5: occupancy-first. R4 (2-stage manual pipeline, ~128+ VGPR) was neutral
// (+15us): per-wave in-flight doubled but waves/CU halved (VGPR tier 128->256).
// Little's law needs only ~9.2 KB in flight per CU -- depth was never the
// limiter. m13's 6.29 TB/s ubench runs ~32 VGPR / 32 waves/CU; R3 ran 16.
// R5 targets VGPR<=64 (launch_bounds(256,8) -> 32 waves/CU):
//   - batch ids staged to LDS once per wave (512 B) -> per-row ids via
//     ds_read (lgkmcnt FIFO), no staged int4 VGPRs, VMEM FIFO = pure data
//   - 8-row blocks (4 dwordx4/lane), wave-uniform fast path when
//     __all(batch[r]==batch[r+7]) (~92% of blocks at avg run len 100):
//     no per-row compares, just 4 loads + 16 v_add_f32
//   - NT hints kept on data (stream-once; R3-with-NT <= R4-without)
//
// Decision gate: if dur_us ~635-655 again, kernel is already ~5.8+ TB/s and
// the rest is harness-fixed (2.048 GB poison fill @ ~318us visible in
// counters + restore/reset) -> declare roofline.

#define FEAT 128
#define ROWS_PER_WAVE 128  // 7813 waves ~= 32/CU resident capacity (8192)

typedef float vfloat4 __attribute__((ext_vector_type(4)));

static __device__ inline vfloat4 ntload4(const float* p) {
  return __builtin_nontemporal_load((const vfloat4*)p);
}

__global__ __launch_bounds__(256, 8) void segsum_kernel(
    const float* __restrict__ h,
    const int* __restrict__ batch,
    float* __restrict__ out,
    int n_rows) {
  __shared__ int bl[4 * ROWS_PER_WAVE];  // 2 KB/block, 4 waves
  const int wid = threadIdx.x >> 6;
  const int wave = (blockIdx.x * blockDim.x + threadIdx.x) >> 6;
  const int lane = threadIdx.x & 63;
  const int sub = lane >> 5;         // which row of the pair this lane covers
  const int col = (lane & 31) * 4;   // 4 consecutive floats (16B coalesced)

  long long row0 = (long long)wave * ROWS_PER_WAVE;
  if (row0 >= n_rows) return;
  long long row_end = row0 + ROWS_PER_WAVE;
  if (row_end > n_rows) row_end = n_rows;

  // Stage this wave's batch slice into LDS (wave-private -> no barrier).
  // Clamp global indices so the last wave never reads past batch[].
  int* myb = bl + wid * ROWS_PER_WAVE;
  {
    long long i0 = row0 + lane;
    long long i1 = row0 + 64 + lane;
    const long long last = (long long)n_rows - 1;
    if (i0 > last) i0 = last;
    if (i1 > last) i1 = last;
    myb[lane] = batch[i0];
    myb[lane + 64] = batch[i1];
  }

  vfloat4 acc = {0.0f, 0.0f, 0.0f, 0.0f};
  int cur = myb[sub];  // batch[row0+sub] (clamped copy is fine)
  float* const outc = out + col;

#define STEP(B, V)                                        \
  {                                                       \
    const int b_ = (B);                                   \
    if (b_ != cur) { /* per-lane, rarely taken */         \
      float* dst = outc + (long long)cur * FEAT;          \
      atomicAdd(dst + 0, acc.x);                          \
      atomicAdd(dst + 1, acc.y);                          \
      atomicAdd(dst + 2, acc.z);                          \
      atomicAdd(dst + 3, acc.w);                          \
      acc.x = 0.0f; acc.y = 0.0f;                         \
      acc.z = 0.0f; acc.w = 0.0f;                         \
      cur = b_;                                           \
    }                                                     \
    acc.x += (V).x; acc.y += (V).y;                       \
    acc.z += (V).z; acc.w += (V).w;                       \
  }

  const float* hp = h + (row0 + sub) * (long long)FEAT + col;
  int li = sub;  // this lane's LDS index for its current row
  long long r = row0;
  const long long nblk = (row_end - row0) >> 3;  // 8-row blocks

  for (long long blk = 0; blk < nblk; ++blk) {
    // 4 x dwordx4 from one base reg with immediate offsets (0/1/2/3 KB)
    vfloat4 v0 = ntload4(hp + 0 * 2 * FEAT);
    vfloat4 v1 = ntload4(hp + 1 * 2 * FEAT);
    vfloat4 v2 = ntload4(hp + 2 * 2 * FEAT);
    vfloat4 v3 = ntload4(hp + 3 * 2 * FEAT);
    // Segment ids for this lane's 4 rows (ds_read2-fusable pairs)
    const int b0 = myb[li + 0];
    const int b1 = myb[li + 2];
    const int b2 = myb[li + 4];
    const int b3 = myb[li + 6];

    if (__all(b0 == b3)) {
      // Whole 8-row block in one segment (sorted: b[r]==b[r+6] &&
      // b[r+1]==b[r+7] => all 8 equal). Wave-uniform branch.
      if (b0 != cur) {
        float* dst = outc + (long long)cur * FEAT;
        atomicAdd(dst + 0, acc.x);
        atomicAdd(dst + 1, acc.y);
        atomicAdd(dst + 2, acc.z);
        atomicAdd(dst + 3, acc.w);
        acc.x = 0.0f; acc.y = 0.0f; acc.z = 0.0f; acc.w = 0.0f;
        cur = b0;
      }
      acc.x += v0.x + v1.x + v2.x + v3.x;
      acc.y += v0.y + v1.y + v2.y + v3.y;
      acc.z += v0.z + v1.z + v2.z + v3.z;
      acc.w += v0.w + v1.w + v2.w + v3.w;
    } else {
      STEP(b0, v0)
      STEP(b1, v1)
      STEP(b2, v2)
      STEP(b3, v3)
    }
    hp += 8 * FEAT;
    li += 8;
    r += 8;
  }

  // Pair tail (none when chunk length is a multiple of 8, generic safety)
  for (; r + 2 <= row_end; r += 2) {
    const int b = myb[li];
    const vfloat4 v = ntload4(hp);
    STEP(b, v)
    hp += 2 * FEAT;
    li += 2;
  }
  // Odd last row
  if (r < row_end && sub == 0) {
    const int b = myb[li];
    const vfloat4 v = ntload4(hp);
    STEP(b, v)
  }
#undef STEP

  // Final flush (run may continue into the next wave's chunk)
  {
    float* dst = outc + (long long)cur * FEAT;
    atomicAdd(dst + 0, acc.x);
    atomicAdd(dst + 1, acc.y);
    atomicAdd(dst + 2, acc.z);
    atomicAdd(dst + 3, acc.w);
  }
}

extern "C" void kernel_launch(void* const* d_in, const int* in_sizes, int n_in,
                              void* d_out, int out_size, void* d_ws, size_t ws_size,
                              hipStream_t stream) {
  const float* h_t = (const float*)d_in[0];
  const int* batch = (const int*)d_in[1];
  float* out = (float*)d_out;
  const int n_rows = in_sizes[1];  // N_NODES

  // d_out is poisoned with 0xAA before every launch — zero it first.
  hipMemsetAsync(d_out, 0, (size_t)out_size * sizeof(float), stream);

  const int n_waves = (n_rows + ROWS_PER_WAVE - 1) / ROWS_PER_WAVE;
  const int block = 256;  // 4 waves/block
  const int waves_per_block = block / 64;
  const int grid = (n_waves + waves_per_block - 1) / waves_per_block;

  segsum_kernel<<<grid, block, 0, stream>>>(h_t, batch, out, n_rows);
}